// Round 11
// baseline (2359.059 us; speedup 1.0000x reference)
//
#include <hip/hip_runtime.h>
#include <math.h>

typedef unsigned short ushort_t;
typedef short short8 __attribute__((ext_vector_type(8)));
typedef float f32x4 __attribute__((ext_vector_type(4)));

#define MFMA16(a,b,c) __builtin_amdgcn_mfma_f32_16x16x32_bf16(a,b,c,0,0,0)

__device__ __forceinline__ ushort_t f2bf(float f){
  unsigned u = __builtin_bit_cast(unsigned, f);
  u += 0x7fffu + ((u >> 16) & 1u);
  return (ushort_t)(u >> 16);
}

__device__ __forceinline__ void gld16(const void* g, void* l){
  __builtin_amdgcn_global_load_lds(
      (const __attribute__((address_space(1))) void*)g,
      (__attribute__((address_space(3))) void*)l, 16, 0, 0);
}

// ---------------- merged weight prep ----------------
__global__ __launch_bounds__(256)
void prep_weights(const float* __restrict__ q_w, const float* __restrict__ kv_w,
                  const float* __restrict__ proj_w, const float* __restrict__ fc1_w,
                  const float* __restrict__ fc2_w, const float* __restrict__ Wm,
                  const float* __restrict__ ln1w, const float* __restrict__ ln2w,
                  ushort_t* __restrict__ q_wb, ushort_t* __restrict__ kv_wb,
                  ushort_t* __restrict__ proj_wb, ushort_t* __restrict__ fc1_wb,
                  ushort_t* __restrict__ fc2_wb, ushort_t* __restrict__ Wt_b)
{
  int i = blockIdx.x*256 + threadIdx.x;
  if (i < 262144){
    q_wb[i] = f2bf(q_w[i] * ln1w[i & 511]);
  } else if (i < 786432){
    int j = i - 262144;
    kv_wb[j] = f2bf(kv_w[j] * ln1w[j & 511]);
  } else if (i < 1048576){
    int j = i - 786432;
    proj_wb[j] = f2bf(proj_w[j]);
  } else if (i < 2097152){
    int j = i - 1048576;
    fc1_wb[j] = f2bf(fc1_w[j] * ln2w[j & 511]);
  } else if (i < 3145728){
    int j = i - 2097152;
    fc2_wb[j] = f2bf(fc2_w[j]);
  } else if (i < 3407872){
    int j = i - 3145728;
    int n = j >> 9, k = j & 511;
    Wt_b[j] = f2bf(Wm[(k << 9) + n]);
  }
}

// merged bias folding: blocks 0..511 q, 512..1535 kv, 1536..3583 fc1
__global__ __launch_bounds__(64)
void prep_bias(const float* __restrict__ q_w, const float* __restrict__ kv_w,
               const float* __restrict__ fc1_w, const float* __restrict__ ln1b,
               const float* __restrict__ ln2b, const float* __restrict__ fc1_b,
               float* __restrict__ qbias, float* __restrict__ kvbias,
               float* __restrict__ fc1bias)
{
  int blk = blockIdx.x, lane = threadIdx.x;
  const float* w; const float* lnb; float* o; float base = 0.f; int n;
  if (blk < 512){ n = blk; w = q_w; lnb = ln1b; o = qbias; }
  else if (blk < 1536){ n = blk - 512; w = kv_w; lnb = ln1b; o = kvbias; }
  else { n = blk - 1536; w = fc1_w; lnb = ln2b; o = fc1bias; }
  float s = 0.f;
  for (int k = lane; k < 512; k += 64) s += w[(size_t)n*512 + k]*lnb[k];
  for (int m = 32; m; m >>= 1) s += __shfl_xor(s, m);
  if (lane == 0){
    if (blk >= 1536) base = fc1_b[n];
    o[n] = s + base;
  }
}

// ---------------- fused LN stats + normalize -> bf16 ----------------
__global__ __launch_bounds__(256)
void lnorm(const float* __restrict__ X, ushort_t* __restrict__ O){
  int row = blockIdx.x*4 + (threadIdx.x >> 6);
  int lane = threadIdx.x & 63;
  const float4* p = (const float4*)(X + (size_t)row*512 + lane*8);
  float4 a = p[0], c = p[1];
  float s = a.x+a.y+a.z+a.w + c.x+c.y+c.z+c.w;
  float q = a.x*a.x+a.y*a.y+a.z*a.z+a.w*a.w + c.x*c.x+c.y*c.y+c.z*c.z+c.w*c.w;
  for (int m = 32; m; m >>= 1){ s += __shfl_xor(s, m); q += __shfl_xor(q, m); }
  float mn = s*(1.f/512.f);
  float rs = rsqrtf(q*(1.f/512.f) - mn*mn + 1e-5f);
  short8 pk;
  pk[0]=(short)f2bf((a.x-mn)*rs); pk[1]=(short)f2bf((a.y-mn)*rs);
  pk[2]=(short)f2bf((a.z-mn)*rs); pk[3]=(short)f2bf((a.w-mn)*rs);
  pk[4]=(short)f2bf((c.x-mn)*rs); pk[5]=(short)f2bf((c.y-mn)*rs);
  pk[6]=(short)f2bf((c.z-mn)*rs); pk[7]=(short)f2bf((c.w-mn)*rs);
  *(short8*)(O + (size_t)row*512 + lane*8) = pk;
}

// ========== GEMM 128x128, BK=32, ring-2 LDS, 5 blocks/CU (TLP-first) ==========
// C[M,N] = A[M,K]*Bt[N,K]^T, bf16 row-major, fp32 accumulate.
// 256 thr = 4 waves (2M x 2N), wave tile 64x64: acc[4][4], per K-step
// 8 ds_read_b128 + 16 MFMA. Ring-2 LDS (2 x 16 KB = 32 KB) staged ONE step
// ahead; one __syncthreads per step (vmcnt0+lgkm0 drain). The drain latency
// is hidden by TLP: 32 KB LDS + launch_bounds(256,5) -> 5 blocks/CU
// (20 waves) — per-block stalls are filled by the other 4 blocks (m114).
// Rotation swizzle (r10-proven, 0 conflicts): stored chunk c of row r holds
// global chunk (c-(r>>1))&3; frag reads at ((lq+(r>>1))&3).
// Staged via pre-rotated GLOBAL source; gld16 dest stays linear (rule #21).
// EPI 0: bf16 out (+bias)             1: fp32 out
// EPI 2: fp32 out = acc+bias+resid    3: bf16 out = gelu(acc+bias)
// EPI 4: KV split: cols<512 -> bf16 K[M,512]; cols>=512 -> Vt[b,h,d,m] (out2)
// EPI 5: fp32 out + fused BN column stats (atomicAdd partials into out2)
template<int EPI>
__global__ __launch_bounds__(256, 5)
void gemm128(const ushort_t* __restrict__ A, const ushort_t* __restrict__ Bt,
             int M, int N, int K,
             const float* __restrict__ bias, const float* __restrict__ resid,
             void* __restrict__ out, void* __restrict__ out2)
{
  constexpr int ASLOT = 128*32;            // ushorts (8 KB)
  constexpr int SLOT  = 2*ASLOT;           // A + B = 16 KB
  __shared__ __align__(16) ushort_t lds[2*SLOT];   // 32 KB

  const int tid  = threadIdx.x;
  const int wave = tid >> 6, lane = tid & 63;
  const int wm   = wave >> 1, wn = wave & 1;
  const int l15  = lane & 15, lq = lane >> 4;

  // bijective XCD swizzle
  const int nwg = gridDim.x;
  const int qc = nwg >> 3, rc = nwg & 7;
  const int xcd = blockIdx.x & 7, sl = blockIdx.x >> 3;
  const int bid = (xcd < rc ? xcd*(qc+1) : rc*(qc+1) + (xcd-rc)*qc) + sl;

  const int tiles_n = N >> 7;
  const int tn = bid % tiles_n, tm = bid / tiles_n;
  const int tileM = tm*128, tileN = tn*128;

  const int r0   = tid >> 2;               // rows 0..63
  const int r1   = (tid + 256) >> 2;       // rows 64..127
  const int g0   = (((tid & 3) - (r0 >> 1)) & 3) * 8;
  const int g1   = (((tid & 3) - (r1 >> 1)) & 3) * 8;
  const ushort_t* Ag0 = A  + (size_t)(tileM + r0)*K + g0;
  const ushort_t* Ag1 = A  + (size_t)(tileM + r1)*K + g1;
  const ushort_t* Bg0 = Bt + (size_t)(tileN + r0)*K + g0;
  const ushort_t* Bg1 = Bt + (size_t)(tileN + r1)*K + g1;

  auto stage = [&](int step, int slot){
    ushort_t* base = lds + slot*SLOT;
    const int k0 = step*32;
    gld16(Ag0 + k0, base + tid*8);
    gld16(Ag1 + k0, base + tid*8 + 2048);
    gld16(Bg0 + k0, base + ASLOT + tid*8);
    gld16(Bg1 + k0, base + ASLOT + tid*8 + 2048);
  };

  int offA[4], offB[4];
#pragma unroll
  for (int mi = 0; mi < 4; mi++){
    int r = wm*64 + mi*16 + l15;
    offA[mi] = r*32 + (((lq + (r >> 1)) & 3) * 8);
  }
#pragma unroll
  for (int ni = 0; ni < 4; ni++){
    int r = wn*64 + ni*16 + l15;
    offB[ni] = ASLOT + r*32 + (((lq + (r >> 1)) & 3) * 8);
  }

  f32x4 acc[4][4] = {};

  const int NT = K >> 5;

  stage(0, 0);
  __syncthreads();

  for (int s = 0; s < NT; ++s){
    if (s + 1 < NT) stage(s + 1, (s + 1) & 1);   // issue early; lands by the
                                                 // end-of-step __syncthreads
    const ushort_t* sb = lds + (s & 1)*SLOT;
    short8 aR[4], bR[4];
#pragma unroll
    for (int mi = 0; mi < 4; mi++) aR[mi] = *(const short8*)(sb + offA[mi]);
#pragma unroll
    for (int ni = 0; ni < 4; ni++) bR[ni] = *(const short8*)(sb + offB[ni]);

    __builtin_amdgcn_s_setprio(1);
#pragma unroll
    for (int mi = 0; mi < 4; mi++)
#pragma unroll
      for (int ni = 0; ni < 4; ni++)
        acc[mi][ni] = MFMA16(aR[mi], bR[ni], acc[mi][ni]);
    __builtin_amdgcn_s_setprio(0);

    __syncthreads();   // drains vmcnt0+lgkm0; TLP (5 blocks) hides the stall
  }

  // ---- epilogue ----
#pragma unroll
  for (int ni = 0; ni < 4; ni++){
    int col = tileN + wn*64 + ni*16 + l15;
    float bv = bias ? bias[col] : 0.f;
    float cs = 0.f, cq = 0.f;
#pragma unroll
    for (int mi = 0; mi < 4; mi++){
      f32x4 v = acc[mi][ni];
      int row0 = tileM + wm*64 + mi*16 + lq*4;
      if constexpr (EPI == 4){
        if (col < 512){
          for (int j = 0; j < 4; j++){
            size_t idx = (size_t)(row0 + j)*512 + col;
            ((ushort_t*)out)[idx] = f2bf(v[j] + bv);
          }
        } else {
          int hh = (col - 512) >> 6, dd = (col - 512) & 63;
          int bb2 = row0 >> 6, mm0 = row0 & 63;
          ushort_t pk[4];
          for (int j = 0; j < 4; j++) pk[j] = f2bf(v[j] + bv);
          *(uint2*)((ushort_t*)out2 + ((((size_t)bb2*8 + hh)*64 + dd) << 6) + mm0) =
              *(const uint2*)pk;
        }
      } else {
        for (int j = 0; j < 4; j++){
          int row = row0 + j;
          size_t idx = (size_t)row*N + col;
          float x = v[j] + bv;
          if constexpr (EPI == 0) ((ushort_t*)out)[idx] = f2bf(x);
          else if constexpr (EPI == 1) ((float*)out)[idx] = x;
          else if constexpr (EPI == 2) ((float*)out)[idx] = x + resid[idx];
          else if constexpr (EPI == 3){
            float g = 0.5f*x*(1.f + erff(x*0.70710678118f));
            ((ushort_t*)out)[idx] = f2bf(g);
          }
          else if constexpr (EPI == 5){
            ((float*)out)[idx] = x;
            cs += x; cq += x*x;
          }
        }
      }
    }
    if constexpr (EPI == 5){
      cs += __shfl_xor(cs, 16); cs += __shfl_xor(cs, 32);
      cq += __shfl_xor(cq, 16); cq += __shfl_xor(cq, 32);
      if (lq == 0){
        float* sums = (float*)out2;
        atomicAdd(&sums[col], cs);
        atomicAdd(&sums[512 + col], cq);
      }
    }
  }
}

// ---------------- batched QK^T ----------------
__global__ __launch_bounds__(256)
void qk_kernel(const ushort_t* __restrict__ Q, const ushort_t* __restrict__ Kb,
               ushort_t* __restrict__ S)
{
  int b = blockIdx.x;
  int wave = threadIdx.x >> 6, lane = threadIdx.x & 63;
  for (int h = wave; h < 8; h += 4){
    f32x4 acc[2][4] = {};
    for (int kk = 0; kk < 2; kk++){
      int kd = kk*32 + (lane >> 4)*8;
      short8 a[2], bb[4];
      for (int mi = 0; mi < 2; mi++){
        int n = mi*16 + (lane & 15); if (n > 16) n = 16;
        a[mi] = *(const short8*)&Q[((size_t)b*17 + n)*512 + h*64 + kd];
      }
      for (int ni = 0; ni < 4; ni++){
        int m = ni*16 + (lane & 15);
        bb[ni] = *(const short8*)&Kb[((size_t)b*64 + m)*512 + h*64 + kd];
      }
      for (int mi = 0; mi < 2; mi++)
        for (int ni = 0; ni < 4; ni++)
          acc[mi][ni] = MFMA16(a[mi], bb[ni], acc[mi][ni]);
    }
    for (int mi = 0; mi < 2; mi++)
      for (int ni = 0; ni < 4; ni++)
        for (int j = 0; j < 4; j++){
          int rr = mi*16 + (lane >> 4)*4 + j;
          if (rr < 17)
            S[((size_t)b*17 + rr)*512 + h*64 + ni*16 + (lane & 15)] =
                f2bf(acc[mi][ni][j]*0.125f);
        }
  }
}

__global__ void bn_finalize(const float* __restrict__ sums, const float* __restrict__ g,
                            const float* __restrict__ b, float* __restrict__ scale,
                            float* __restrict__ shift, float invN){
  int c = blockIdx.x*256 + threadIdx.x;
  if (c < 512){
    float mean = sums[c]*invN;
    float var  = sums[512 + c]*invN - mean*mean;
    float sc = g[c]*rsqrtf(var + 1e-5f);
    scale[c] = sc; shift[c] = b[c] - mean*sc;
  }
}

// ---------------- fused BN apply + adjacency + softmax + PV ----------------
// P kept in LDS (row stride 520 ushorts: 1040B -> bank shift 4/row, breaks
// the 1KB-stride same-bank pattern), then PV MFMA reads P from LDS and Vt
// from global. Removes the 72 MB Asm round-trip and one dispatch.
__constant__ unsigned ADJM[17] = {
  0x7u, 0xFu, 0x17u, 0x2Au, 0x54u, 0x8E8u, 0x1170u, 0x2A0u, 0x540u,
  0x280u, 0x500u, 0x3820u, 0x5840u, 0xA800u, 0x15000u, 0xA000u, 0x14000u };

__global__ __launch_bounds__(256)
void bnadj_softmax_pv(const float* __restrict__ preBN, const float* __restrict__ scale,
                      const float* __restrict__ shift, const ushort_t* __restrict__ Vt,
                      ushort_t* __restrict__ X)
{
  __shared__ float yt[17*512];
  __shared__ __align__(16) ushort_t pl[17*520];
  int b = blockIdx.x, tid = threadIdx.x;
  const float* src = preBN + (size_t)b*17*512;
  for (int i = tid; i < 17*512; i += 256){
    int c = i & 511;
    yt[i] = src[i]*scale[c] + shift[c];
  }
  __syncthreads();
  int qw = tid >> 4, l16 = tid & 15;
  for (int g = qw; g < 136; g += 16){
    int n = g >> 3, h = g & 7;
    float z[4];
    unsigned msk = ADJM[n];
    for (int u = 0; u < 4; u++){
      int c = h*64 + l16 + u*16;
      float sv = 0.f;
      unsigned mm = msk;
      while (mm){ int j = __ffs(mm) - 1; mm &= mm - 1; sv += yt[j*512 + c]; }
      z[u] = sv;
    }
    float mx = fmaxf(fmaxf(z[0], z[1]), fmaxf(z[2], z[3]));
    for (int m = 8; m; m >>= 1) mx = fmaxf(mx, __shfl_xor(mx, m, 16));
    float e0 = expf(z[0]-mx), e1 = expf(z[1]-mx), e2 = expf(z[2]-mx), e3 = expf(z[3]-mx);
    float ss = e0 + e1 + e2 + e3;
    for (int m = 8; m; m >>= 1) ss += __shfl_xor(ss, m, 16);
    float inv = 1.f/ss;
    int ob = n*520 + h*64 + l16;
    pl[ob]      = f2bf(e0*inv);
    pl[ob + 16] = f2bf(e1*inv);
    pl[ob + 32] = f2bf(e2*inv);
    pl[ob + 48] = f2bf(e3*inv);
  }
  __syncthreads();

  // PV: X[b,n,h*64+d] = sum_m P[n,h*64+m] * Vt[b,h,d,m]
  int wave = tid >> 6, lane = tid & 63;
  for (int h = wave; h < 8; h += 4){
    f32x4 acc[2][4] = {};
    for (int kk = 0; kk < 2; kk++){
      int km = kk*32 + (lane >> 4)*8;
      short8 a[2], bb[4];
      for (int mi = 0; mi < 2; mi++){
        int n = mi*16 + (lane & 15); if (n > 16) n = 16;
        a[mi] = *(const short8*)&pl[n*520 + h*64 + km];
      }
      for (int ni = 0; ni < 4; ni++){
        int d = ni*16 + (lane & 15);
        bb[ni] = *(const short8*)&Vt[(((size_t)b*8 + h)*64 + d)*64 + km];
      }
      for (int mi = 0; mi < 2; mi++)
        for (int ni = 0; ni < 4; ni++)
          acc[mi][ni] = MFMA16(a[mi], bb[ni], acc[mi][ni]);
    }
    for (int mi = 0; mi < 2; mi++)
      for (int ni = 0; ni < 4; ni++)
        for (int j = 0; j < 4; j++){
          int rr = mi*16 + (lane >> 4)*4 + j;
          if (rr < 17)
            X[((size_t)b*17 + rr)*512 + h*64 + ni*16 + (lane & 15)] =
                f2bf(acc[mi][ni][j]);
        }
  }
}

// ---------------- host ----------------
extern "C" void kernel_launch(void* const* d_in, const int* in_sizes, int n_in,
                              void* d_out, int out_size, void* d_ws, size_t ws_size,
                              hipStream_t stream)
{
  const float* noise  = (const float*)d_in[0];
  const float* obj    = (const float*)d_in[1];
  const float* ln1w   = (const float*)d_in[2];
  const float* ln1b   = (const float*)d_in[3];
  const float* ln2w   = (const float*)d_in[4];
  const float* ln2b   = (const float*)d_in[5];
  const float* q_w    = (const float*)d_in[6];
  const float* kv_w   = (const float*)d_in[7];
  const float* Wm     = (const float*)d_in[8];
  const float* bn_g   = (const float*)d_in[9];
  const float* bn_b   = (const float*)d_in[10];
  const float* proj_w = (const float*)d_in[11];
  const float* proj_b = (const float*)d_in[12];
  const float* fc1_w  = (const float*)d_in[13];
  const float* fc1_b  = (const float*)d_in[14];
  const float* fc2_w  = (const float*)d_in[15];
  const float* fc2_b  = (const float*)d_in[16];

  const int B  = in_sizes[0] / (17*512);   // 2048
  const int M  = B*17;                     // 34816
  const int MO = B*64;                     // 131072

  const size_t MiB = 1ull << 20;
  char* ws = (char*)d_ws;

  ushort_t* q_wb    = (ushort_t*)(ws + 0*MiB);
  ushort_t* kv_wb   = (ushort_t*)(ws + 1*MiB);
  ushort_t* proj_wb = (ushort_t*)(ws + 2*MiB);
  ushort_t* fc1_wb  = (ushort_t*)(ws + 3*MiB);
  ushort_t* fc2_wb  = (ushort_t*)(ws + 5*MiB);
  ushort_t* Wt_b    = (ushort_t*)(ws + 7*MiB);
  float* qbias   = (float*)(ws + 7*MiB + 600*1024);
  float* kvbias  = qbias + 1024;
  float* fc1bias = kvbias + 1024;
  float* bnsum   = fc1bias + 2048;
  float* bnscale = bnsum + 1024;
  float* bnshift = bnscale + 512;

  char* R1 = ws + 8*MiB;
  char* R2 = ws + 136*MiB;
  char* R3 = ws + 264*MiB;

  ushort_t* e1b  = (ushort_t*)R1;
  ushort_t* Kb   = (ushort_t*)R2;
  ushort_t* Vtb  = (ushort_t*)R3;
  ushort_t* x1b  = (ushort_t*)R1;
  ushort_t* Qb   = (ushort_t*)(R1 + 35*MiB);
  ushort_t* Sb   = (ushort_t*)(R1 + 70*MiB);
  ushort_t* PVo  = (ushort_t*)(R1 + 35*MiB);   // reuses Q region (Q dead)
  float*    preBN = (float*)R2;
  float*    xres  = (float*)R2;
  ushort_t* yb   = (ushort_t*)(R2 + 69*MiB);
  ushort_t* h1   = (ushort_t*)(R2 + 104*MiB);
  float*    outp = (float*)d_out;

  // ---- prep ----
  hipMemsetAsync(bnsum, 0, 1024*4, stream);
  prep_weights<<<dim3(3407872/256), 256, 0, stream>>>(
      q_w, kv_w, proj_w, fc1_w, fc2_w, Wm, ln1w, ln2w,
      q_wb, kv_wb, proj_wb, fc1_wb, fc2_wb, Wt_b);
  prep_bias<<<dim3(3584), 64, 0, stream>>>(
      q_w, kv_w, fc1_w, ln1b, ln2b, fc1_b, qbias, kvbias, fc1bias);

  // ---- attention branch ----
  lnorm<<<dim3(MO/4), 256, 0, stream>>>(obj, e1b);
  gemm128<4><<<dim3((MO/128)*(1024/128)), 256, 0, stream>>>(
      e1b, kv_wb, MO, 1024, 512, kvbias, nullptr, Kb, Vtb);
  lnorm<<<dim3(M/4), 256, 0, stream>>>(noise, x1b);
  gemm128<0><<<dim3((M/128)*(512/128)), 256, 0, stream>>>(
      x1b, q_wb, M, 512, 512, qbias, nullptr, Qb, nullptr);
  qk_kernel<<<dim3(B), 256, 0, stream>>>(Qb, Kb, Sb);
  gemm128<5><<<dim3((M/128)*(512/128)), 256, 0, stream>>>(
      Sb, Wt_b, M, 512, 512, nullptr, nullptr, preBN, bnsum);
  bn_finalize<<<dim3(2), 256, 0, stream>>>(bnsum, bn_g, bn_b, bnscale, bnshift, 1.f/(float)M);
  bnadj_softmax_pv<<<dim3(B), 256, 0, stream>>>(preBN, bnscale, bnshift, Vtb, PVo);
  gemm128<2><<<dim3((M/128)*(512/128)), 256, 0, stream>>>(
      PVo, proj_wb, M, 512, 512, proj_b, noise, xres, nullptr);

  // ---- MLP branch ----
  lnorm<<<dim3(M/4), 256, 0, stream>>>(xres, yb);
  gemm128<3><<<dim3((M/128)*(2048/128)), 256, 0, stream>>>(
      yb, fc1_wb, M, 2048, 512, fc1bias, nullptr, h1, nullptr);
  gemm128<2><<<dim3((M/128)*(512/128)), 256, 0, stream>>>(
      h1, fc2_wb, M, 512, 2048, fc2_b, xres, outp, nullptr);
}

// Round 12
// 799.010 us; speedup vs baseline: 2.9525x; 2.9525x over previous
//
#include <hip/hip_runtime.h>
#include <math.h>

typedef unsigned short ushort_t;
typedef short short8 __attribute__((ext_vector_type(8)));
typedef float f32x4 __attribute__((ext_vector_type(4)));

#define MFMA16(a,b,c) __builtin_amdgcn_mfma_f32_16x16x32_bf16(a,b,c,0,0,0)

__device__ __forceinline__ ushort_t f2bf(float f){
  unsigned u = __builtin_bit_cast(unsigned, f);
  u += 0x7fffu + ((u >> 16) & 1u);
  return (ushort_t)(u >> 16);
}

__device__ __forceinline__ void gld16(const void* g, void* l){
  __builtin_amdgcn_global_load_lds(
      (const __attribute__((address_space(1))) void*)g,
      (__attribute__((address_space(3))) void*)l, 16, 0, 0);
}

// ---------------- merged weight prep ----------------
__global__ __launch_bounds__(256)
void prep_weights(const float* __restrict__ q_w, const float* __restrict__ kv_w,
                  const float* __restrict__ proj_w, const float* __restrict__ fc1_w,
                  const float* __restrict__ fc2_w, const float* __restrict__ Wm,
                  const float* __restrict__ ln1w, const float* __restrict__ ln2w,
                  ushort_t* __restrict__ q_wb, ushort_t* __restrict__ kv_wb,
                  ushort_t* __restrict__ proj_wb, ushort_t* __restrict__ fc1_wb,
                  ushort_t* __restrict__ fc2_wb, ushort_t* __restrict__ Wt_b)
{
  int i = blockIdx.x*256 + threadIdx.x;
  if (i < 262144){
    q_wb[i] = f2bf(q_w[i] * ln1w[i & 511]);
  } else if (i < 786432){
    int j = i - 262144;
    kv_wb[j] = f2bf(kv_w[j] * ln1w[j & 511]);
  } else if (i < 1048576){
    int j = i - 786432;
    proj_wb[j] = f2bf(proj_w[j]);
  } else if (i < 2097152){
    int j = i - 1048576;
    fc1_wb[j] = f2bf(fc1_w[j] * ln2w[j & 511]);
  } else if (i < 3145728){
    int j = i - 2097152;
    fc2_wb[j] = f2bf(fc2_w[j]);
  } else if (i < 3407872){
    int j = i - 3145728;
    int n = j >> 9, k = j & 511;
    Wt_b[j] = f2bf(Wm[(k << 9) + n]);
  }
}

// merged bias folding: blocks 0..511 q, 512..1535 kv, 1536..3583 fc1
__global__ __launch_bounds__(64)
void prep_bias(const float* __restrict__ q_w, const float* __restrict__ kv_w,
               const float* __restrict__ fc1_w, const float* __restrict__ ln1b,
               const float* __restrict__ ln2b, const float* __restrict__ fc1_b,
               float* __restrict__ qbias, float* __restrict__ kvbias,
               float* __restrict__ fc1bias)
{
  int blk = blockIdx.x, lane = threadIdx.x;
  const float* w; const float* lnb; float* o; float base = 0.f; int n;
  if (blk < 512){ n = blk; w = q_w; lnb = ln1b; o = qbias; }
  else if (blk < 1536){ n = blk - 512; w = kv_w; lnb = ln1b; o = kvbias; }
  else { n = blk - 1536; w = fc1_w; lnb = ln2b; o = fc1bias; }
  float s = 0.f;
  for (int k = lane; k < 512; k += 64) s += w[(size_t)n*512 + k]*lnb[k];
  for (int m = 32; m; m >>= 1) s += __shfl_xor(s, m);
  if (lane == 0){
    if (blk >= 1536) base = fc1_b[n];
    o[n] = s + base;
  }
}

// ---------------- fused LN stats + normalize -> bf16 ----------------
__global__ __launch_bounds__(256)
void lnorm(const float* __restrict__ X, ushort_t* __restrict__ O){
  int row = blockIdx.x*4 + (threadIdx.x >> 6);
  int lane = threadIdx.x & 63;
  const float4* p = (const float4*)(X + (size_t)row*512 + lane*8);
  float4 a = p[0], c = p[1];
  float s = a.x+a.y+a.z+a.w + c.x+c.y+c.z+c.w;
  float q = a.x*a.x+a.y*a.y+a.z*a.z+a.w*a.w + c.x*c.x+c.y*c.y+c.z*c.z+c.w*c.w;
  for (int m = 32; m; m >>= 1){ s += __shfl_xor(s, m); q += __shfl_xor(q, m); }
  float mn = s*(1.f/512.f);
  float rs = rsqrtf(q*(1.f/512.f) - mn*mn + 1e-5f);
  short8 pk;
  pk[0]=(short)f2bf((a.x-mn)*rs); pk[1]=(short)f2bf((a.y-mn)*rs);
  pk[2]=(short)f2bf((a.z-mn)*rs); pk[3]=(short)f2bf((a.w-mn)*rs);
  pk[4]=(short)f2bf((c.x-mn)*rs); pk[5]=(short)f2bf((c.y-mn)*rs);
  pk[6]=(short)f2bf((c.z-mn)*rs); pk[7]=(short)f2bf((c.w-mn)*rs);
  *(short8*)(O + (size_t)row*512 + lane*8) = pk;
}

// ========== GEMM 256x128 ring-3, counted vmcnt, (512,4) — r6-proven ==========
// Used for the kv projection (M=131072, N=1024): best measured kv kernel.
template<int BN, int EPI>
__global__ __launch_bounds__(512, 4)
void gemm256(const ushort_t* __restrict__ A, const ushort_t* __restrict__ Bt,
             int M, int N, int K,
             const float* __restrict__ bias, const float* __restrict__ resid,
             void* __restrict__ out, void* __restrict__ out2)
{
  constexpr int NR    = BN / 64;
  constexpr int ASLOT = 256 * 32;
  constexpr int BSLOT = BN * 32;
  constexpr int SLOT  = ASLOT + BSLOT;
  __shared__ __align__(16) ushort_t lds[3 * SLOT];

  const int tid  = threadIdx.x;
  const int wave = tid >> 6, lane = tid & 63;
  const int wm   = wave >> 2, wn = wave & 3;
  const int l15  = lane & 15, lq = lane >> 4;

  const int nwg = gridDim.x;
  const int qc = nwg >> 3, rc = nwg & 7;
  const int xcd = blockIdx.x & 7, sl = blockIdx.x >> 3;
  const int bid = (xcd < rc ? xcd*(qc+1) : rc*(qc+1) + (xcd-rc)*qc) + sl;

  const int tiles_n = N / BN;
  const int tn = bid % tiles_n, tm = bid / tiles_n;
  const int tileM = tm * 256, tileN = tn * BN;

  const int gsw = (((tid & 3) - ((tid >> 3) & 3)) & 3) * 8;
  const int srow = tid >> 2;

  int offA[8], offB[NR];
#pragma unroll
  for (int mi = 0; mi < 8; mi++){
    int r = wm*128 + mi*16 + l15;
    offA[mi] = r*32 + (((lq + (r >> 1)) & 3) * 8);
  }
#pragma unroll
  for (int ni = 0; ni < NR; ni++){
    int r = wn*(BN/4) + ni*16 + l15;
    offB[ni] = ASLOT + r*32 + (((lq + (r >> 1)) & 3) * 8);
  }

  f32x4 acc[8][NR] = {};

  const int NT = K >> 5;

  auto stage = [&](int step, int slot){
    ushort_t* base = lds + slot * SLOT;
    const int k0 = step * 32 + gsw;
#pragma unroll
    for (int i = 0; i < 2; i++)
      gld16(A + (size_t)(tileM + i*128 + srow)*K + k0,
            base + i*4096 + wave*512);
#pragma unroll
    for (int i = 0; i < BN/128; i++)
      gld16(Bt + (size_t)(tileN + i*128 + srow)*K + k0,
            base + ASLOT + i*4096 + wave*512);
  };

  stage(0, 0);
  stage(1, 1);
  if constexpr (BN == 256) asm volatile("s_waitcnt vmcnt(4)" ::: "memory");
  else                     asm volatile("s_waitcnt vmcnt(3)" ::: "memory");
  __builtin_amdgcn_sched_barrier(0);
  __builtin_amdgcn_s_barrier();

  int rs = 0;
  for (int s = 0; s < NT; ++s){
    const ushort_t* sb = lds + rs * SLOT;
    short8 bfr[NR];
#pragma unroll
    for (int ni = 0; ni < NR; ni++)
      bfr[ni] = *(const short8*)(sb + offB[ni]);

    const bool more = (s + 2 < NT);
    if (more){
      int r2 = rs + 2; if (r2 >= 3) r2 -= 3;
      stage(s + 2, r2);
    }

    __builtin_amdgcn_s_setprio(1);
#pragma unroll
    for (int mi = 0; mi < 8; mi++){
      short8 af = *(const short8*)(sb + offA[mi]);
#pragma unroll
      for (int ni = 0; ni < NR; ni++)
        acc[mi][ni] = MFMA16(af, bfr[ni], acc[mi][ni]);
    }
    __builtin_amdgcn_s_setprio(0);

    if (more){
      if constexpr (BN == 256) asm volatile("s_waitcnt vmcnt(4)" ::: "memory");
      else                     asm volatile("s_waitcnt vmcnt(3)" ::: "memory");
    } else {
      asm volatile("s_waitcnt vmcnt(0)" ::: "memory");
    }
    __builtin_amdgcn_sched_barrier(0);
    __builtin_amdgcn_s_barrier();

    rs = (rs == 2) ? 0 : rs + 1;
  }

  // epilogue
#pragma unroll
  for (int ni = 0; ni < NR; ni++){
    int col = tileN + wn*(BN/4) + ni*16 + l15;
    float bv = bias ? bias[col] : 0.f;
    float cs = 0.f, cq = 0.f;
#pragma unroll
    for (int mi = 0; mi < 8; mi++){
      f32x4 v = acc[mi][ni];
      int row0 = tileM + wm*128 + mi*16 + lq*4;
      if constexpr (EPI == 4){
        if (col < 512){
          for (int j = 0; j < 4; j++){
            size_t idx = (size_t)(row0 + j)*512 + col;
            ((ushort_t*)out)[idx] = f2bf(v[j] + bv);
          }
        } else {
          int hh = (col - 512) >> 6, dd = (col - 512) & 63;
          int bb2 = row0 >> 6, mm0 = row0 & 63;
          ushort_t pk[4];
          for (int j = 0; j < 4; j++) pk[j] = f2bf(v[j] + bv);
          *(uint2*)((ushort_t*)out2 + ((((size_t)bb2*8 + hh)*64 + dd) << 6) + mm0) =
              *(const uint2*)pk;
        }
      } else {
        for (int j = 0; j < 4; j++){
          int row = row0 + j;
          size_t idx = (size_t)row*N + col;
          float x = v[j] + bv;
          if constexpr (EPI == 0) ((ushort_t*)out)[idx] = f2bf(x);
          else if constexpr (EPI == 1) ((float*)out)[idx] = x;
          else if constexpr (EPI == 2) ((float*)out)[idx] = x + resid[idx];
          else if constexpr (EPI == 3){
            float g = 0.5f*x*(1.f + erff(x*0.70710678118f));
            ((ushort_t*)out)[idx] = f2bf(g);
          }
          else if constexpr (EPI == 5){
            ((float*)out)[idx] = x;
            cs += x; cq += x*x;
          }
        }
      }
    }
    if constexpr (EPI == 5){
      cs += __shfl_xor(cs, 16); cs += __shfl_xor(cs, 32);
      cq += __shfl_xor(cq, 16); cq += __shfl_xor(cq, 32);
      if (lq == 0){
        float* sums = (float*)out2;
        atomicAdd(&sums[col], cs);
        atomicAdd(&sums[512 + col], cq);
      }
    }
  }
}

// ========== GEMM 128x128, BK=32, ring-3, (256,3) — r10-proven ==========
template<int EPI>
__global__ __launch_bounds__(256, 3)
void gemm128(const ushort_t* __restrict__ A, const ushort_t* __restrict__ Bt,
             int M, int N, int K,
             const float* __restrict__ bias, const float* __restrict__ resid,
             void* __restrict__ out, void* __restrict__ out2)
{
  constexpr int ASLOT = 128*32;            // ushorts (8 KB)
  constexpr int SLOT  = 2*ASLOT;           // A + B = 16 KB
  __shared__ __align__(16) ushort_t lds[3*SLOT];

  const int tid  = threadIdx.x;
  const int wave = tid >> 6, lane = tid & 63;
  const int wm   = wave >> 1, wn = wave & 1;
  const int l15  = lane & 15, lq = lane >> 4;

  const int nwg = gridDim.x;
  const int qc = nwg >> 3, rc = nwg & 7;
  const int xcd = blockIdx.x & 7, sl = blockIdx.x >> 3;
  const int bid = (xcd < rc ? xcd*(qc+1) : rc*(qc+1) + (xcd-rc)*qc) + sl;

  const int tiles_n = N >> 7;
  const int tn = bid % tiles_n, tm = bid / tiles_n;
  const int tileM = tm*128, tileN = tn*128;

  const int r0   = tid >> 2;               // rows 0..63
  const int r1   = (tid + 256) >> 2;       // rows 64..127
  const int g0   = (((tid & 3) - (r0 >> 1)) & 3) * 8;
  const int g1   = (((tid & 3) - (r1 >> 1)) & 3) * 8;
  const ushort_t* Ag0 = A  + (size_t)(tileM + r0)*K + g0;
  const ushort_t* Ag1 = A  + (size_t)(tileM + r1)*K + g1;
  const ushort_t* Bg0 = Bt + (size_t)(tileN + r0)*K + g0;
  const ushort_t* Bg1 = Bt + (size_t)(tileN + r1)*K + g1;

  auto stage = [&](int step, int slot){
    ushort_t* base = lds + slot*SLOT;
    const int k0 = step*32;
    gld16(Ag0 + k0, base + tid*8);
    gld16(Ag1 + k0, base + tid*8 + 2048);
    gld16(Bg0 + k0, base + ASLOT + tid*8);
    gld16(Bg1 + k0, base + ASLOT + tid*8 + 2048);
  };

  int offA[4], offB[4];
#pragma unroll
  for (int mi = 0; mi < 4; mi++){
    int r = wm*64 + mi*16 + l15;
    offA[mi] = r*32 + (((lq + (r >> 1)) & 3) * 8);
  }
#pragma unroll
  for (int ni = 0; ni < 4; ni++){
    int r = wn*64 + ni*16 + l15;
    offB[ni] = ASLOT + r*32 + (((lq + (r >> 1)) & 3) * 8);
  }

  f32x4 acc[4][4] = {};

  const int NT = K >> 5;

  stage(0, 0);
  stage(1, 1);
  asm volatile("s_waitcnt vmcnt(4)" ::: "memory");
  __builtin_amdgcn_sched_barrier(0);
  __builtin_amdgcn_s_barrier();
  __builtin_amdgcn_sched_barrier(0);

  int rs = 0;
  for (int s = 0; s < NT; ++s){
    const ushort_t* sb = lds + rs*SLOT;
    short8 aR[4], bR[4];
#pragma unroll
    for (int mi = 0; mi < 4; mi++) aR[mi] = *(const short8*)(sb + offA[mi]);
#pragma unroll
    for (int ni = 0; ni < 4; ni++) bR[ni] = *(const short8*)(sb + offB[ni]);

    const bool more = (s + 2 < NT);
    if (more){
      int r2 = rs + 2; if (r2 >= 3) r2 -= 3;
      stage(s + 2, r2);
    }

    __builtin_amdgcn_s_setprio(1);
#pragma unroll
    for (int mi = 0; mi < 4; mi++)
#pragma unroll
      for (int ni = 0; ni < 4; ni++)
        acc[mi][ni] = MFMA16(aR[mi], bR[ni], acc[mi][ni]);
    __builtin_amdgcn_s_setprio(0);

    if (more){
      asm volatile("s_waitcnt vmcnt(4)" ::: "memory");
    } else {
      asm volatile("s_waitcnt vmcnt(0)" ::: "memory");
    }
    __builtin_amdgcn_sched_barrier(0);
    __builtin_amdgcn_s_barrier();
    __builtin_amdgcn_sched_barrier(0);

    rs = (rs == 2) ? 0 : rs + 1;
  }

  // ---- epilogue ----
#pragma unroll
  for (int ni = 0; ni < 4; ni++){
    int col = tileN + wn*64 + ni*16 + l15;
    float bv = bias ? bias[col] : 0.f;
    float cs = 0.f, cq = 0.f;
#pragma unroll
    for (int mi = 0; mi < 4; mi++){
      f32x4 v = acc[mi][ni];
      int row0 = tileM + wm*64 + mi*16 + lq*4;
      if constexpr (EPI == 4){
        if (col < 512){
          for (int j = 0; j < 4; j++){
            size_t idx = (size_t)(row0 + j)*512 + col;
            ((ushort_t*)out)[idx] = f2bf(v[j] + bv);
          }
        } else {
          int hh = (col - 512) >> 6, dd = (col - 512) & 63;
          int bb2 = row0 >> 6, mm0 = row0 & 63;
          ushort_t pk[4];
          for (int j = 0; j < 4; j++) pk[j] = f2bf(v[j] + bv);
          *(uint2*)((ushort_t*)out2 + ((((size_t)bb2*8 + hh)*64 + dd) << 6) + mm0) =
              *(const uint2*)pk;
        }
      } else {
        for (int j = 0; j < 4; j++){
          int row = row0 + j;
          size_t idx = (size_t)row*N + col;
          float x = v[j] + bv;
          if constexpr (EPI == 0) ((ushort_t*)out)[idx] = f2bf(x);
          else if constexpr (EPI == 1) ((float*)out)[idx] = x;
          else if constexpr (EPI == 2) ((float*)out)[idx] = x + resid[idx];
          else if constexpr (EPI == 3){
            float g = 0.5f*x*(1.f + erff(x*0.70710678118f));
            ((ushort_t*)out)[idx] = f2bf(g);
          }
          else if constexpr (EPI == 5){
            ((float*)out)[idx] = x;
            cs += x; cq += x*x;
          }
        }
      }
    }
    if constexpr (EPI == 5){
      cs += __shfl_xor(cs, 16); cs += __shfl_xor(cs, 32);
      cq += __shfl_xor(cq, 16); cq += __shfl_xor(cq, 32);
      if (lq == 0){
        float* sums = (float*)out2;
        atomicAdd(&sums[col], cs);
        atomicAdd(&sums[512 + col], cq);
      }
    }
  }
}

// ---------------- batched QK^T ----------------
__global__ __launch_bounds__(256)
void qk_kernel(const ushort_t* __restrict__ Q, const ushort_t* __restrict__ Kb,
               ushort_t* __restrict__ S)
{
  int b = blockIdx.x;
  int wave = threadIdx.x >> 6, lane = threadIdx.x & 63;
  for (int h = wave; h < 8; h += 4){
    f32x4 acc[2][4] = {};
    for (int kk = 0; kk < 2; kk++){
      int kd = kk*32 + (lane >> 4)*8;
      short8 a[2], bb[4];
      for (int mi = 0; mi < 2; mi++){
        int n = mi*16 + (lane & 15); if (n > 16) n = 16;
        a[mi] = *(const short8*)&Q[((size_t)b*17 + n)*512 + h*64 + kd];
      }
      for (int ni = 0; ni < 4; ni++){
        int m = ni*16 + (lane & 15);
        bb[ni] = *(const short8*)&Kb[((size_t)b*64 + m)*512 + h*64 + kd];
      }
      for (int mi = 0; mi < 2; mi++)
        for (int ni = 0; ni < 4; ni++)
          acc[mi][ni] = MFMA16(a[mi], bb[ni], acc[mi][ni]);
    }
    for (int mi = 0; mi < 2; mi++)
      for (int ni = 0; ni < 4; ni++)
        for (int j = 0; j < 4; j++){
          int rr = mi*16 + (lane >> 4)*4 + j;
          if (rr < 17)
            S[((size_t)b*17 + rr)*512 + h*64 + ni*16 + (lane & 15)] =
                f2bf(acc[mi][ni][j]*0.125f);
        }
  }
}

// ---------------- fused BN finalize+apply + adjacency + softmax + PV ----------------
__constant__ unsigned ADJM[17] = {
  0x7u, 0xFu, 0x17u, 0x2Au, 0x54u, 0x8E8u, 0x1170u, 0x2A0u, 0x540u,
  0x280u, 0x500u, 0x3820u, 0x5840u, 0xA800u, 0x15000u, 0xA000u, 0x14000u };

__global__ __launch_bounds__(256)
void bnadj_softmax_pv(const float* __restrict__ preBN, const float* __restrict__ bnsum,
                      const float* __restrict__ bn_g, const float* __restrict__ bn_b,
                      float invN, const ushort_t* __restrict__ Vt,
                      ushort_t* __restrict__ X)
{
  __shared__ float yt[17*512];
  __shared__ __align__(16) ushort_t pl[17*520];
  int b = blockIdx.x, tid = threadIdx.x;

  // inline bn_finalize: this thread's 2 columns (c = tid, tid+256)
  float sc[2], sh[2];
#pragma unroll
  for (int j = 0; j < 2; j++){
    int c = tid + j*256;
    float mean = bnsum[c]*invN;
    float var  = bnsum[512 + c]*invN - mean*mean;
    float s = bn_g[c]*rsqrtf(var + 1e-5f);
    sc[j] = s; sh[j] = bn_b[c] - mean*s;
  }

  const float* src = preBN + (size_t)b*17*512;
  for (int k = 0; k < 34; k++){
    int i = tid + k*256;
    yt[i] = src[i]*sc[k & 1] + sh[k & 1];
  }
  __syncthreads();
  int qw = tid >> 4, l16 = tid & 15;
  for (int g = qw; g < 136; g += 16){
    int n = g >> 3, h = g & 7;
    float z[4];
    unsigned msk = ADJM[n];
    for (int u = 0; u < 4; u++){
      int c = h*64 + l16 + u*16;
      float sv = 0.f;
      unsigned mm = msk;
      while (mm){ int j = __ffs(mm) - 1; mm &= mm - 1; sv += yt[j*512 + c]; }
      z[u] = sv;
    }
    float mx = fmaxf(fmaxf(z[0], z[1]), fmaxf(z[2], z[3]));
    for (int m = 8; m; m >>= 1) mx = fmaxf(mx, __shfl_xor(mx, m, 16));
    float e0 = expf(z[0]-mx), e1 = expf(z[1]-mx), e2 = expf(z[2]-mx), e3 = expf(z[3]-mx);
    float ss = e0 + e1 + e2 + e3;
    for (int m = 8; m; m >>= 1) ss += __shfl_xor(ss, m, 16);
    float inv = 1.f/ss;
    int ob = n*520 + h*64 + l16;
    pl[ob]      = f2bf(e0*inv);
    pl[ob + 16] = f2bf(e1*inv);
    pl[ob + 32] = f2bf(e2*inv);
    pl[ob + 48] = f2bf(e3*inv);
  }
  __syncthreads();

  // PV: X[b,n,h*64+d] = sum_m P[n,h*64+m] * Vt[b,h,d,m]
  int wave = tid >> 6, lane = tid & 63;
  for (int h = wave; h < 8; h += 4){
    f32x4 acc[2][4] = {};
    for (int kk = 0; kk < 2; kk++){
      int km = kk*32 + (lane >> 4)*8;
      short8 a[2], bb[4];
      for (int mi = 0; mi < 2; mi++){
        int n = mi*16 + (lane & 15); if (n > 16) n = 16;
        a[mi] = *(const short8*)&pl[n*520 + h*64 + km];
      }
      for (int ni = 0; ni < 4; ni++){
        int d = ni*16 + (lane & 15);
        bb[ni] = *(const short8*)&Vt[(((size_t)b*8 + h)*64 + d)*64 + km];
      }
      for (int mi = 0; mi < 2; mi++)
        for (int ni = 0; ni < 4; ni++)
          acc[mi][ni] = MFMA16(a[mi], bb[ni], acc[mi][ni]);
    }
    for (int mi = 0; mi < 2; mi++)
      for (int ni = 0; ni < 4; ni++)
        for (int j = 0; j < 4; j++){
          int rr = mi*16 + (lane >> 4)*4 + j;
          if (rr < 17)
            X[((size_t)b*17 + rr)*512 + h*64 + ni*16 + (lane & 15)] =
                f2bf(acc[mi][ni][j]);
        }
  }
}

// ---------------- host ----------------
extern "C" void kernel_launch(void* const* d_in, const int* in_sizes, int n_in,
                              void* d_out, int out_size, void* d_ws, size_t ws_size,
                              hipStream_t stream)
{
  const float* noise  = (const float*)d_in[0];
  const float* obj    = (const float*)d_in[1];
  const float* ln1w   = (const float*)d_in[2];
  const float* ln1b   = (const float*)d_in[3];
  const float* ln2w   = (const float*)d_in[4];
  const float* ln2b   = (const float*)d_in[5];
  const float* q_w    = (const float*)d_in[6];
  const float* kv_w   = (const float*)d_in[7];
  const float* Wm     = (const float*)d_in[8];
  const float* bn_g   = (const float*)d_in[9];
  const float* bn_b   = (const float*)d_in[10];
  const float* proj_w = (const float*)d_in[11];
  const float* proj_b = (const float*)d_in[12];
  const float* fc1_w  = (const float*)d_in[13];
  const float* fc1_b  = (const float*)d_in[14];
  const float* fc2_w  = (const float*)d_in[15];
  const float* fc2_b  = (const float*)d_in[16];

  const int B  = in_sizes[0] / (17*512);   // 2048
  const int M  = B*17;                     // 34816
  const int MO = B*64;                     // 131072

  const size_t MiB = 1ull << 20;
  char* ws = (char*)d_ws;

  ushort_t* q_wb    = (ushort_t*)(ws + 0*MiB);
  ushort_t* kv_wb   = (ushort_t*)(ws + 1*MiB);
  ushort_t* proj_wb = (ushort_t*)(ws + 2*MiB);
  ushort_t* fc1_wb  = (ushort_t*)(ws + 3*MiB);
  ushort_t* fc2_wb  = (ushort_t*)(ws + 5*MiB);
  ushort_t* Wt_b    = (ushort_t*)(ws + 7*MiB);
  float* qbias   = (float*)(ws + 7*MiB + 600*1024);
  float* kvbias  = qbias + 1024;
  float* fc1bias = kvbias + 1024;
  float* bnsum   = fc1bias + 2048;

  char* R1 = ws + 8*MiB;
  char* R2 = ws + 136*MiB;
  char* R3 = ws + 264*MiB;

  ushort_t* e1b  = (ushort_t*)R1;
  ushort_t* Kb   = (ushort_t*)R2;
  ushort_t* Vtb  = (ushort_t*)R3;
  ushort_t* x1b  = (ushort_t*)R1;
  ushort_t* Qb   = (ushort_t*)(R1 + 35*MiB);
  ushort_t* Sb   = (ushort_t*)(R1 + 70*MiB);
  ushort_t* PVo  = (ushort_t*)(R1 + 35*MiB);   // reuses Q region (Q dead)
  float*    preBN = (float*)R2;
  float*    xres  = (float*)R2;
  ushort_t* yb   = (ushort_t*)(R2 + 69*MiB);
  ushort_t* h1   = (ushort_t*)(R2 + 104*MiB);
  float*    outp = (float*)d_out;

  // ---- prep ----
  hipMemsetAsync(bnsum, 0, 1024*4, stream);
  prep_weights<<<dim3(3407872/256), 256, 0, stream>>>(
      q_w, kv_w, proj_w, fc1_w, fc2_w, Wm, ln1w, ln2w,
      q_wb, kv_wb, proj_wb, fc1_wb, fc2_wb, Wt_b);
  prep_bias<<<dim3(3584), 64, 0, stream>>>(
      q_w, kv_w, fc1_w, ln1b, ln2b, fc1_b, qbias, kvbias, fc1bias);

  // ---- attention branch ----
  lnorm<<<dim3(MO/4), 256, 0, stream>>>(obj, e1b);
  gemm256<128,4><<<dim3((MO/256)*(1024/128)), 512, 0, stream>>>(
      e1b, kv_wb, MO, 1024, 512, kvbias, nullptr, Kb, Vtb);
  lnorm<<<dim3(M/4), 256, 0, stream>>>(noise, x1b);
  gemm128<0><<<dim3((M/128)*(512/128)), 256, 0, stream>>>(
      x1b, q_wb, M, 512, 512, qbias, nullptr, Qb, nullptr);
  qk_kernel<<<dim3(B), 256, 0, stream>>>(Qb, Kb, Sb);
  gemm128<5><<<dim3((M/128)*(512/128)), 256, 0, stream>>>(
      Sb, Wt_b, M, 512, 512, nullptr, nullptr, preBN, bnsum);
  bnadj_softmax_pv<<<dim3(B), 256, 0, stream>>>(
      preBN, bnsum, bn_g, bn_b, 1.f/(float)M, Vtb, PVo);
  gemm128<2><<<dim3((M/128)*(512/128)), 256, 0, stream>>>(
      PVo, proj_wb, M, 512, 512, proj_b, noise, xres, nullptr);

  // ---- MLP branch ----
  lnorm<<<dim3(M/4), 256, 0, stream>>>(xres, yb);
  gemm128<3><<<dim3((M/128)*(2048/128)), 256, 0, stream>>>(
      yb, fc1_wb, M, 2048, 512, fc1bias, nullptr, h1, nullptr);
  gemm128<2><<<dim3((M/128)*(512/128)), 256, 0, stream>>>(
      h1, fc2_wb, M, 512, 2048, fc2_b, xres, outp, nullptr);
}